// Round 7
// baseline (135.326 us; speedup 1.0000x reference)
//
#include <hip/hip_runtime.h>
#include <hip/hip_bf16.h>

// CoincidenceDetector: S[b,n] = sum_d |w_d| * [|q-pt|<5] * exp(-|q-pt|/3)
// pt = 20 - 15*sigmoid(patterns)
//
// exp(-|dt|/3) = min(Eq*ip0, Iq*ep0), Eq=e^{q/3}, ep0=e^{pt/3} (w-free).
// Window |dt|<5 <=> k0 > theta = e^{-5/3} (literal cmp); weight by fma(|w|).
//
// R7 vs R6 (63.5us): R6 was LDS-PIPE bound -- uniform ds_read_b128 broadcasts
// deliver 16B/instr of a 1KB/instr pipe shared by 4 SIMDs (2.1M reads x 12cyc
// / 256 CU = 41us > 20.5us VALU floor). Fix: query side via SGPR s_load
// (readfirstlane-uniform addr, manual 1-chunk double-buffer to hide latency),
// pattern side precomputed ONCE to ws as f16 pairs (kills the x4-redundant
// transcendental staging too). Zero LDS. Hot loop: 6 VALU/elem, all regs.

static constexpr float kC2    = 0.48089834696298783f;   // 1/(3*ln2)
static constexpr float kL2E   = 1.4426950408889634f;    // log2(e)
static constexpr float kTheta = 0.18887560283756183f;   // exp(-5/3)

#define B_   64
#define N_   16384
#define D_   256
#define NCH  64      // d-chunks of 4

// ---------- pre: pattern side -> f16 ep0/ip0, layout [dc][n][8 f16] ----------
__global__ __launch_bounds__(256) void pre_pattern(const float* __restrict__ patterns,
                                                   _Float16* __restrict__ pat2) {
    const int n = blockIdx.x;          // 0..16383
    const int d = threadIdx.x;         // 0..255
    float x  = patterns[(size_t)n * D_ + d];
    float t  = exp2f(-x * kL2E);                    // e^{-x}
    float sg = __fdividef(1.0f, 1.0f + t);          // sigmoid
    float u  = fmaf(-15.0f * kC2, sg, 20.0f * kC2); // pt/(3 ln2)
    float e0 = exp2f(u);
    float i0 = exp2f(-u);
    int dc = d >> 2, j = d & 3;
    size_t base = ((size_t)dc * N_ + n) * 8;
    pat2[base + j]     = (_Float16)e0;
    pat2[base + 4 + j] = (_Float16)i0;
}

// ---------- pre: query side -> f32 [dc][bg(16)][b4(4)][j(4)][2] ----------
__global__ __launch_bounds__(256) void pre_query(const float* __restrict__ q,
                                                 float* __restrict__ qarr) {
    const int b = blockIdx.x;          // 0..63
    const int d = threadIdx.x;         // 0..255
    float qv = q[(size_t)b * D_ + d];
    float u  = qv * kC2;
    int dc = d >> 2, j = d & 3, bg = b >> 2, b4 = b & 3;
    size_t idx = ((size_t)(dc * 16 + bg) << 5) + b4 * 8 + j * 2;
    qarr[idx]     = exp2f(u);    // Eq
    qarr[idx + 1] = exp2f(-u);   // Iq
}

// ---------- main ----------
struct QBuf { float q[32]; float w[4]; };

__device__ __forceinline__ void load_q(const float* __restrict__ qarr,
                                       const float* __restrict__ weights,
                                       int dc, int bg, QBuf& o) {
    const float* p = qarr + ((size_t)(dc * 16 + bg) << 5);   // uniform -> s_load
#pragma unroll
    for (int j = 0; j < 32; ++j) o.q[j] = p[j];
#pragma unroll
    for (int j = 0; j < 4; ++j) o.w[j] = fabsf(weights[dc * 4 + j]);
}

__device__ __forceinline__ void chunk_math(const QBuf& Q, uint4 r0, uint4 r1,
                                           float acc[2][4]) {
    union Cv { uint4 u; _Float16 h[8]; };
    Cv c0, c1; c0.u = r0; c1.u = r1;
    float ep[2][4], ip[2][4];
#pragma unroll
    for (int j = 0; j < 4; ++j) {
        ep[0][j] = (float)c0.h[j];  ip[0][j] = (float)c0.h[j + 4];
        ep[1][j] = (float)c1.h[j];  ip[1][j] = (float)c1.h[j + 4];
    }
#pragma unroll
    for (int b = 0; b < 4; ++b) {
#pragma unroll
        for (int j = 0; j < 4; ++j) {
            float Eq = Q.q[b * 8 + j * 2];
            float Iq = Q.q[b * 8 + j * 2 + 1];
#pragma unroll
            for (int r = 0; r < 2; ++r) {
                float a = Eq * ip[r][j];            // v_mul (1 sgpr)
                float c = Iq * ep[r][j];            // v_mul (1 sgpr)
                float k = fminf(a, c);              // v_min
                float m = (k > kTheta) ? k : 0.0f;  // v_cmp(lit) + v_cndmask
                acc[r][b] = fmaf(m, Q.w[j], acc[r][b]); // v_fma (1 sgpr)
            }
        }
    }
}

__global__ __launch_bounds__(256, 2) void cd_main(
        const uint4* __restrict__ pat2,     // [dc][n] of 8 f16
        const float* __restrict__ qarr,     // [dc][bg][32]
        const float* __restrict__ weights,
        float* __restrict__ S) {
    const int l    = threadIdx.x & 63;
    const int wv   = threadIdx.x >> 6;
    const int nt   = blockIdx.x >> 2;                 // 0..127
    const int bsub = blockIdx.x & 3;                  // 0..3
    const int bg   = __builtin_amdgcn_readfirstlane(bsub * 4 + wv); // 0..15
    const int b0   = bg * 4;
    const int n0   = nt * 128;
    const int row0 = n0 + l, row1 = n0 + 64 + l;

    float acc[2][4];
#pragma unroll
    for (int r = 0; r < 2; ++r)
#pragma unroll
        for (int b = 0; b < 4; ++b) acc[r][b] = 0.0f;

    QBuf qA, qB;
    uint4 pA0, pA1, pB0, pB1;
    load_q(qarr, weights, 0, bg, qA);
    pA0 = pat2[(size_t)0 * N_ + row0];
    pA1 = pat2[(size_t)0 * N_ + row1];

    for (int dc = 0; dc < NCH - 2; dc += 2) {
        // prefetch dc+1
        load_q(qarr, weights, dc + 1, bg, qB);
        pB0 = pat2[(size_t)(dc + 1) * N_ + row0];
        pB1 = pat2[(size_t)(dc + 1) * N_ + row1];
        chunk_math(qA, pA0, pA1, acc);
        // prefetch dc+2
        load_q(qarr, weights, dc + 2, bg, qA);
        pA0 = pat2[(size_t)(dc + 2) * N_ + row0];
        pA1 = pat2[(size_t)(dc + 2) * N_ + row1];
        chunk_math(qB, pB0, pB1, acc);
    }
    // tail: dc = 62 staged in A; stage 63 then finish
    load_q(qarr, weights, NCH - 1, bg, qB);
    pB0 = pat2[(size_t)(NCH - 1) * N_ + row0];
    pB1 = pat2[(size_t)(NCH - 1) * N_ + row1];
    chunk_math(qA, pA0, pA1, acc);
    chunk_math(qB, pB0, pB1, acc);

    // stores: coalesced per (r,b)
#pragma unroll
    for (int r = 0; r < 2; ++r)
#pragma unroll
        for (int b = 0; b < 4; ++b)
            S[(size_t)(b0 + b) * N_ + n0 + r * 64 + l] = acc[r][b];
}

extern "C" void kernel_launch(void* const* d_in, const int* in_sizes, int n_in,
                              void* d_out, int out_size, void* d_ws, size_t ws_size,
                              hipStream_t stream) {
    const float* q        = (const float*)d_in[0];
    const float* patterns = (const float*)d_in[1];
    const float* weights  = (const float*)d_in[2];
    float* S = (float*)d_out;

    // ws: qarr (131072 B) first, then pat2 (16777216 B) -> need 16908288 B
    // (byte-identical to R2's proven-available ws usage)
    float*    qarr = (float*)d_ws;
    _Float16* pat2 = (_Float16*)((char*)d_ws + (size_t)NCH * 16 * 32 * 4);

    pre_pattern<<<N_, 256, 0, stream>>>(patterns, pat2);
    pre_query  <<<B_, 256, 0, stream>>>(q, qarr);
    cd_main    <<<512, 256, 0, stream>>>((const uint4*)pat2, qarr, weights, S);
}

// Round 10
// 128.294 us; speedup vs baseline: 1.0548x; 1.0548x over previous
//
#include <hip/hip_runtime.h>
#include <hip/hip_bf16.h>

// CoincidenceDetector: S[b,n] = sum_d |w_d| * [|q-pt|<5] * exp(-|q-pt|/3)
// pt = 20 - 15*sigmoid(patterns)
//
// exp(-|dt|/3) = min(Eq*ip0, Iq*ep0); window <=> k0 > theta (literal);
// weight applied by fma(|w|). 6 full-rate VALU / element, register-only.
//
// R10 = R8 resubmitted verbatim after two infra failures (container death,
// then GPU-acquisition timeout; kernel never measured). R8 rationale vs R7
// (55us, occ 17%, FETCH 33MB): R7 was latency-bound at 2 waves/SIMD with
// pat2 served from L3 (bsub-siblings on different XCDs). Fixes:
//  (1) 1 row/lane -> grid 1024 = 4 blocks/CU = 4 waves/SIMD (TLP x2)
//  (2) pat2 relayout [nt][dc][row] (contiguous 64KB/block tile) + block order
//      bsub*256+nt so the 4 sibling blocks share an XCD -> L2 hits
//  (3) pre_pattern rewritten: coalesced 16B reads AND 16B uint4 writes
//      (R7's 2-byte scattered stores cost ~80us of the 135us total)

static constexpr float kC2    = 0.48089834696298783f;   // 1/(3*ln2)
static constexpr float kL2E   = 1.4426950408889634f;    // log2(e)
static constexpr float kTheta = 0.18887560283756183f;   // exp(-5/3)

#define B_   64
#define N_   16384
#define D_   256
#define NCH  64      // d-chunks of 4
#define NTL  256     // n-tiles of 64 rows

// ---------- pre: pattern side -> f16 ep0/ip0, layout [nt][dc][row][8 f16] ----
__global__ __launch_bounds__(256) void pre_pattern(const float* __restrict__ patterns,
                                                   uint4* __restrict__ pat2) {
    const int nt  = blockIdx.x;        // 0..255
    const int tid = threadIdx.x;
#pragma unroll
    for (int it = 0; it < 16; ++it) {
        int idx = it * 256 + tid;      // (row,dc) granule id 0..4095
        int dc  = idx >> 6;            // 0..63
        int row = idx & 63;            // consecutive lanes -> coalesced writes
        float4 x4 = *(const float4*)&patterns[((size_t)nt * 64 + row) * D_ + dc * 4];
        float xs[4] = {x4.x, x4.y, x4.z, x4.w};
        union { uint4 u; _Float16 h[8]; } o;
#pragma unroll
        for (int j = 0; j < 4; ++j) {
            float t  = exp2f(-xs[j] * kL2E);                // e^{-x}
            float sg = __fdividef(1.0f, 1.0f + t);          // sigmoid
            float u  = fmaf(-15.0f * kC2, sg, 20.0f * kC2); // pt/(3 ln2)
            o.h[j]     = (_Float16)exp2f(u);                // ep0
            o.h[4 + j] = (_Float16)exp2f(-u);               // ip0
        }
        pat2[(size_t)nt * 4096 + dc * 64 + row] = o.u;      // 16B coalesced
    }
}

// ---------- pre: query side -> f32 [dc][bg(16)][b4(4)][j(4)][2] ----------
__global__ __launch_bounds__(256) void pre_query(const float* __restrict__ q,
                                                 float* __restrict__ qarr) {
    const int b = blockIdx.x;          // 0..63
    const int d = threadIdx.x;         // 0..255
    float qv = q[(size_t)b * D_ + d];
    float u  = qv * kC2;
    int dc = d >> 2, j = d & 3, bg = b >> 2, b4 = b & 3;
    size_t idx = ((size_t)(dc * 16 + bg) << 5) + b4 * 8 + j * 2;
    qarr[idx]     = exp2f(u);    // Eq
    qarr[idx + 1] = exp2f(-u);   // Iq
}

// ---------- main ----------
struct QBuf { float q[32]; float w[4]; };

__device__ __forceinline__ void load_q(const float* __restrict__ qarr,
                                       const float* __restrict__ weights,
                                       int dc, int bg, QBuf& o) {
    const float* p = qarr + ((size_t)(dc * 16 + bg) << 5);   // uniform -> s_load
#pragma unroll
    for (int j = 0; j < 32; ++j) o.q[j] = p[j];
#pragma unroll
    for (int j = 0; j < 4; ++j) o.w[j] = fabsf(weights[dc * 4 + j]);
}

__device__ __forceinline__ void chunk_math(const QBuf& Q, uint4 r0, float acc[4]) {
    union { uint4 u; _Float16 h[8]; } c; c.u = r0;
    float ep[4], ip[4];
#pragma unroll
    for (int j = 0; j < 4; ++j) {
        ep[j] = (float)c.h[j];
        ip[j] = (float)c.h[j + 4];
    }
#pragma unroll
    for (int b = 0; b < 4; ++b) {
#pragma unroll
        for (int j = 0; j < 4; ++j) {
            float a = Q.q[b * 8 + j * 2]     * ip[j];   // v_mul (sgpr)
            float c2 = Q.q[b * 8 + j * 2 + 1] * ep[j];  // v_mul (sgpr)
            float k = fminf(a, c2);                     // v_min
            float m = (k > kTheta) ? k : 0.0f;          // v_cmp(lit)+v_cndmask
            acc[b] = fmaf(m, Q.w[j], acc[b]);           // v_fma (sgpr)
        }
    }
}

__global__ __launch_bounds__(256, 4) void cd_main(
        const uint4* __restrict__ pat2,     // [nt][dc][row] of 8 f16
        const float* __restrict__ qarr,     // [dc][bg][32]
        const float* __restrict__ weights,
        float* __restrict__ S) {
    const int l    = threadIdx.x & 63;
    const int wv   = threadIdx.x >> 6;
    const int nt   = blockIdx.x & 255;                // idx%8 = nt%8 -> same-XCD siblings
    const int bsub = blockIdx.x >> 8;                 // 0..3
    const int bg   = __builtin_amdgcn_readfirstlane(bsub * 4 + wv); // 0..15
    const int b0   = bg * 4;

    const uint4* pbase = pat2 + (size_t)nt * 4096 + l;  // lane row, SGPR-friendly

    float acc[4] = {0.f, 0.f, 0.f, 0.f};

    QBuf qA, qB;
    uint4 pA, pB;
    load_q(qarr, weights, 0, bg, qA);
    pA = pbase[0];

    for (int dc = 0; dc < NCH - 2; dc += 2) {
        load_q(qarr, weights, dc + 1, bg, qB);
        pB = pbase[(dc + 1) * 64];
        chunk_math(qA, pA, acc);
        load_q(qarr, weights, dc + 2, bg, qA);
        pA = pbase[(dc + 2) * 64];
        chunk_math(qB, pB, acc);
    }
    load_q(qarr, weights, NCH - 1, bg, qB);
    pB = pbase[(NCH - 1) * 64];
    chunk_math(qA, pA, acc);      // chunk 62
    chunk_math(qB, pB, acc);      // chunk 63

#pragma unroll
    for (int b = 0; b < 4; ++b)
        S[(size_t)(b0 + b) * N_ + nt * 64 + l] = acc[b];
}

extern "C" void kernel_launch(void* const* d_in, const int* in_sizes, int n_in,
                              void* d_out, int out_size, void* d_ws, size_t ws_size,
                              hipStream_t stream) {
    const float* q        = (const float*)d_in[0];
    const float* patterns = (const float*)d_in[1];
    const float* weights  = (const float*)d_in[2];
    float* S = (float*)d_out;

    // ws: qarr (131072 B) then pat2 (16777216 B) -> 16908288 B (proven fits)
    float* qarr = (float*)d_ws;
    uint4* pat2 = (uint4*)((char*)d_ws + (size_t)NCH * 16 * 32 * 4);

    pre_pattern<<<NTL, 256, 0, stream>>>(patterns, pat2);
    pre_query  <<<B_,  256, 0, stream>>>(q, qarr);
    cd_main    <<<1024, 256, 0, stream>>>(pat2, qarr, weights, S);
}

// Round 11
// 110.656 us; speedup vs baseline: 1.2229x; 1.1594x over previous
//
#include <hip/hip_runtime.h>
#include <hip/hip_bf16.h>

// CoincidenceDetector: S[b,n] = sum_d |w_d| * [|q-pt|<5] * exp(-|q-pt|/3)
// pt = 20 - 15*sigmoid(patterns)
//
// exp(-|dt|/3) = min(Eq*ip0, Iq*ep0); window <=> m > theta*|w| (strict);
// weight applied inside v_dot2_f32_f16 (pair-reduce into f32 acc).
//
// R11 vs R10 (55us, invariant across occupancy x2 and FETCH /3.5 => issue-
// count bound is the remaining hypothesis): packed-f16 math, 3.5 VALU/elem:
//   per d-pair: pk_mul, pk_mul, pk_min, pk_sub(theta_w - m),
//   pk_ashrrev_i16(sign->mask), v_and(m,mask), v_dot2_f32_f16(m', w, acc)
// pat2's uint4 IS the packed operand (no unpack cvts). Query side f16 pairs
// via SGPR s_load (uniform). 2 b/wave -> grid 2048 = 8 blocks/CU = 8 w/SIMD.

#include <stdint.h>

typedef _Float16 h2  __attribute__((ext_vector_type(2)));
typedef short    s2v __attribute__((ext_vector_type(2)));

static constexpr float kC2    = 0.48089834696298783f;   // 1/(3*ln2)
static constexpr float kL2E   = 1.4426950408889634f;    // log2(e)
static constexpr float kTheta = 0.18887560283756183f;   // exp(-5/3)

#define B_   64
#define N_   16384
#define D_   256
#define NCH  64      // d-chunks of 4
#define NTL  256     // n-tiles of 64 rows

union HU { uint32_t u; h2 h; s2v s; };
__device__ __forceinline__ h2 uh(uint32_t x) { HU c; c.u = x; return c.h; }

// ---------- pre: pattern side -> f16 ep0/ip0, layout [nt][dc][row][8 f16] ----
// uint4 = {ep(d0,d1), ep(d2,d3), ip(d0,d1), ip(d2,d3)}
__global__ __launch_bounds__(256) void pre_pattern(const float* __restrict__ patterns,
                                                   uint4* __restrict__ pat2) {
    const int nt = blockIdx.x >> 2;
    const int qq = blockIdx.x & 3;
#pragma unroll
    for (int it = 0; it < 4; ++it) {
        int g   = qq * 1024 + it * 256 + threadIdx.x;   // granule 0..4095
        int dc  = g >> 6;
        int row = g & 63;              // consecutive lanes -> coalesced writes
        float4 x4 = *(const float4*)&patterns[((size_t)nt * 64 + row) * D_ + dc * 4];
        float xs[4] = {x4.x, x4.y, x4.z, x4.w};
        union { uint4 u; _Float16 h[8]; } o;
#pragma unroll
        for (int j = 0; j < 4; ++j) {
            float t  = exp2f(-xs[j] * kL2E);                // e^{-x}
            float sg = __fdividef(1.0f, 1.0f + t);          // sigmoid
            float u  = fmaf(-15.0f * kC2, sg, 20.0f * kC2); // pt/(3 ln2)
            o.h[j]     = (_Float16)exp2f(u);                // ep0
            o.h[4 + j] = (_Float16)exp2f(-u);               // ip0
        }
        pat2[(size_t)nt * 4096 + dc * 64 + row] = o.u;
    }
}

// ---------- pre: query side -> f16 [dc][bg2(32)]{eq dwords 0..3, iq 4..7}
// dword j = (b2*2+p); also wtab[dc] = {thw pair0, thw pair1, w pair0, w pair1}
__global__ __launch_bounds__(256) void pre_query(const float* __restrict__ q,
                                                 const float* __restrict__ w,
                                                 _Float16* __restrict__ qh,
                                                 _Float16* __restrict__ wh) {
    const int b = blockIdx.x;          // 0..63
    const int d = threadIdx.x;         // 0..255
    float qv = q[(size_t)b * D_ + d];
    float u  = qv * kC2;
    int dc = d >> 2, p = (d >> 1) & 1, hh = d & 1, bg2 = b >> 1, b2 = b & 1;
    size_t base = (size_t)(dc * 32 + bg2) * 16;        // 8 dwords = 16 halfs
    qh[base + (size_t)(b2 * 2 + p) * 2 + hh]     = (_Float16)exp2f(u);   // Eq
    qh[base + 8 + (size_t)(b2 * 2 + p) * 2 + hh] = (_Float16)exp2f(-u);  // Iq
    if (b == 0) {
        float wa = fabsf(w[d]);
        wh[dc * 8 + p * 2 + hh]     = (_Float16)(kTheta * wa);  // theta*|w|
        wh[dc * 8 + 4 + p * 2 + hh] = (_Float16)wa;             // |w|
    }
}

// ---------- main ----------
struct QB { uint32_t eq[4]; uint32_t iq[4]; };   // [b2*2+p]
struct WB { uint32_t tw[2]; uint32_t w[2]; };    // [p]

__device__ __forceinline__ void load_q(const uint32_t* __restrict__ qarr,
                                       const uint32_t* __restrict__ wtab,
                                       int dc, int bg2, QB& o, WB& wo) {
    const uint32_t* p = qarr + (size_t)(dc * 32 + bg2) * 8;   // uniform -> s_load
#pragma unroll
    for (int j = 0; j < 4; ++j) o.eq[j] = p[j];
#pragma unroll
    for (int j = 0; j < 4; ++j) o.iq[j] = p[4 + j];
    const uint32_t* wp = wtab + dc * 4;                        // uniform -> s_load
    wo.tw[0] = wp[0]; wo.tw[1] = wp[1]; wo.w[0] = wp[2]; wo.w[1] = wp[3];
}

__device__ __forceinline__ void chunk_math(const QB& Q, const WB& W, uint4 P,
                                           float acc[2]) {
    h2 ep[2] = {uh(P.x), uh(P.y)};
    h2 ip[2] = {uh(P.z), uh(P.w)};
#pragma unroll
    for (int b2 = 0; b2 < 2; ++b2) {
#pragma unroll
        for (int p = 0; p < 2; ++p) {
            h2 a = uh(Q.eq[b2 * 2 + p]) * ip[p];   // v_pk_mul_f16 (sgpr)
            h2 c = uh(Q.iq[b2 * 2 + p]) * ep[p];   // v_pk_mul_f16 (sgpr)
            h2 m = __builtin_elementwise_min(a, c);// v_pk_min_f16
            h2 t = uh(W.tw[p]) - m;                // v_pk_add_f16 neg (sgpr)
            HU tm; tm.h = t;
            tm.s = tm.s >> 15;                     // v_pk_ashrrev_i16: FFFF iff m>tw
            HU mm; mm.h = m;
            mm.u &= tm.u;                          // v_and_b32: masked m
#if __has_builtin(__builtin_amdgcn_fdot2)
            acc[b2] = __builtin_amdgcn_fdot2(mm.h, uh(W.w[p]), acc[b2], false);
#else
            h2 wp2 = uh(W.w[p]);
            acc[b2] = fmaf((float)mm.h.x, (float)wp2.x,
                      fmaf((float)mm.h.y, (float)wp2.y, acc[b2]));
#endif
        }
    }
}

__global__ __launch_bounds__(256, 8) void cd_main(
        const uint4* __restrict__ pat2,       // [nt][dc][row] of 8 f16
        const uint32_t* __restrict__ qarr,    // [dc][bg2][8 dwords]
        const uint32_t* __restrict__ wtab,    // [dc][4 dwords]
        float* __restrict__ S) {
    const int l    = threadIdx.x & 63;
    const int wv   = threadIdx.x >> 6;
    const int nt   = blockIdx.x & 255;        // idx%8 = nt%8 -> same-XCD siblings
    const int bsub = blockIdx.x >> 8;         // 0..7
    const int bg2  = __builtin_amdgcn_readfirstlane(bsub * 4 + wv); // 0..31
    const int b0   = bg2 * 2;

    const uint4* pbase = pat2 + (size_t)nt * 4096 + l;

    float acc[2] = {0.f, 0.f};

    QB qA, qB; WB wA, wB;
    uint4 pA, pB;
    load_q(qarr, wtab, 0, bg2, qA, wA);
    pA = pbase[0];

    for (int dc = 0; dc < NCH - 2; dc += 2) {
        load_q(qarr, wtab, dc + 1, bg2, qB, wB);
        pB = pbase[(dc + 1) * 64];
        chunk_math(qA, wA, pA, acc);
        load_q(qarr, wtab, dc + 2, bg2, qA, wA);
        pA = pbase[(dc + 2) * 64];
        chunk_math(qB, wB, pB, acc);
    }
    load_q(qarr, wtab, NCH - 1, bg2, qB, wB);
    pB = pbase[(NCH - 1) * 64];
    chunk_math(qA, wA, pA, acc);      // chunk 62
    chunk_math(qB, wB, pB, acc);      // chunk 63

    S[(size_t)b0 * N_ + nt * 64 + l]       = acc[0];
    S[(size_t)(b0 + 1) * N_ + nt * 64 + l] = acc[1];
}

extern "C" void kernel_launch(void* const* d_in, const int* in_sizes, int n_in,
                              void* d_out, int out_size, void* d_ws, size_t ws_size,
                              hipStream_t stream) {
    const float* q        = (const float*)d_in[0];
    const float* patterns = (const float*)d_in[1];
    const float* weights  = (const float*)d_in[2];
    float* S = (float*)d_out;

    // ws: qarr 65536 B | wtab 1024 B | pat2 16777216 B -> 16843776 B total
    // (R2 proved >= 16908288 B available)
    uint32_t* qarr = (uint32_t*)d_ws;
    uint32_t* wtab = (uint32_t*)((char*)d_ws + 65536);
    uint4*    pat2 = (uint4*)((char*)d_ws + 65536 + 1024);

    pre_pattern<<<NTL * 4, 256, 0, stream>>>(patterns, pat2);
    pre_query  <<<B_,      256, 0, stream>>>(q, weights,
                                             (_Float16*)qarr, (_Float16*)wtab);
    cd_main    <<<2048,    256, 0, stream>>>(pat2, qarr, wtab, S);
}

// Round 12
// 109.461 us; speedup vs baseline: 1.2363x; 1.0109x over previous
//
#include <hip/hip_runtime.h>
#include <stdint.h>

// CoincidenceDetector: S[b,n] = sum_d |w_d| * [|q-pt|<5] * exp(-|q-pt|/3)
// pt = 20 - 15*sigmoid(patterns)
//
// exp(-|dt|/3) = min(Eq*ip0, Iq*ep0); window <=> m > theta*|w| via f16
// sign-mask (strict); weight applied inside v_dot2_f32_f16. 3.5 VALU/elem.
//
// R12 vs R11 (cd_main ~40us inferred, 3x above 12us packed-issue floor):
// suspected staller = main-loop global pat2 stream (8x duplicated tile/CU,
// L1-thrashed -> L2 latency) + separate latency-bound pre_pattern kernel.
// Fix: FUSE staging into cd_main. Block (nt,bh) stages its 64x256 pattern
// tile straight into 64KB LDS as packed f16 (coalesced f4 reads, XOR-swizzle
// ds_write_b128), then 8 waves x 4 b x 64 chunks: per chunk 1 ds_read_b128
// (conflict-free) + dbuf s_load (20 dwords) + 112 issue-cycles of packed
// math -> cover ratio > 1. pat2/pre_pattern gone; ws = 65KB.

typedef _Float16 h2  __attribute__((ext_vector_type(2)));
typedef short    s2v __attribute__((ext_vector_type(2)));

static constexpr float kC2    = 0.48089834696298783f;   // 1/(3*ln2)
static constexpr float kL2E   = 1.4426950408889634f;    // log2(e)
static constexpr float kTheta = 0.18887560283756183f;   // exp(-5/3)

#define B_   64
#define N_   16384
#define D_   256
#define NCH  64      // d-chunks of 4

union HU { uint32_t u; h2 h; s2v s; };
__device__ __forceinline__ h2 uh(uint32_t x) { HU c; c.u = x; return c.h; }

// ---------- pre: query side -> f16. qarr [dc][bg(16)][16 dwords]:
// dwords 0..7 = Eq(b4,p), 8..15 = Iq(b4,p). wtab [dc][4 dwords]: tw pair0/1, w pair0/1.
__global__ __launch_bounds__(256) void pre_query(const float* __restrict__ q,
                                                 const float* __restrict__ w,
                                                 _Float16* __restrict__ qh,
                                                 _Float16* __restrict__ wh) {
    const int b = blockIdx.x;          // 0..63
    const int d = threadIdx.x;         // 0..255
    float qv = q[(size_t)b * D_ + d];
    float u  = qv * kC2;
    int dc = d >> 2, p = (d >> 1) & 1, hh = d & 1, bg = b >> 2, b4 = b & 3;
    size_t base = (size_t)(dc * 16 + bg) * 32;     // half-index (16 dwords)
    qh[base + (size_t)(b4 * 2 + p) * 2 + hh]      = (_Float16)exp2f(u);   // Eq
    qh[base + 16 + (size_t)(b4 * 2 + p) * 2 + hh] = (_Float16)exp2f(-u);  // Iq
    if (b == 0) {
        float wa = fabsf(w[d]);
        wh[dc * 8 + p * 2 + hh]     = (_Float16)(kTheta * wa);  // theta*|w|
        wh[dc * 8 + 4 + p * 2 + hh] = (_Float16)wa;             // |w|
    }
}

// ---------- main ----------
struct QB { uint32_t eq[8]; uint32_t iq[8]; };   // [b4*2+p]
struct WB { uint32_t tw[2]; uint32_t w[2]; };    // [p]

__device__ __forceinline__ void load_q(const uint32_t* __restrict__ qarr,
                                       const uint32_t* __restrict__ wtab,
                                       int dc, int bg, QB& o, WB& wo) {
    const uint32_t* p = qarr + (size_t)(dc * 16 + bg) * 16;   // uniform -> s_load
#pragma unroll
    for (int j = 0; j < 8; ++j) o.eq[j] = p[j];
#pragma unroll
    for (int j = 0; j < 8; ++j) o.iq[j] = p[8 + j];
    const uint32_t* wp = wtab + dc * 4;                        // uniform -> s_load
    wo.tw[0] = wp[0]; wo.tw[1] = wp[1]; wo.w[0] = wp[2]; wo.w[1] = wp[3];
}

__device__ __forceinline__ void chunk_math(const QB& Q, const WB& W, uint4 P,
                                           float acc[4]) {
    h2 ep[2] = {uh(P.x), uh(P.y)};
    h2 ip[2] = {uh(P.z), uh(P.w)};
#pragma unroll
    for (int b4 = 0; b4 < 4; ++b4) {
#pragma unroll
        for (int p = 0; p < 2; ++p) {
            h2 a = uh(Q.eq[b4 * 2 + p]) * ip[p];   // v_pk_mul_f16 (sgpr)
            h2 c = uh(Q.iq[b4 * 2 + p]) * ep[p];   // v_pk_mul_f16 (sgpr)
            h2 m = __builtin_elementwise_min(a, c);// v_pk_min_f16
            h2 t = uh(W.tw[p]) - m;                // v_pk_add_f16 neg (sgpr)
            HU tm; tm.h = t;
            tm.s = tm.s >> 15;                     // v_pk_ashrrev_i16: FFFF iff m>tw
            HU mm; mm.h = m;
            mm.u &= tm.u;                          // v_and_b32
#if __has_builtin(__builtin_amdgcn_fdot2)
            acc[b4] = __builtin_amdgcn_fdot2(mm.h, uh(W.w[p]), acc[b4], false);
#else
            h2 wp2 = uh(W.w[p]);
            acc[b4] = fmaf((float)mm.h.x, (float)wp2.x,
                      fmaf((float)mm.h.y, (float)wp2.y, acc[b4]));
#endif
        }
    }
}

__global__ __launch_bounds__(512, 4) void cd_main(
        const float* __restrict__ patterns,
        const uint32_t* __restrict__ qarr,    // [dc][bg][16 dwords]
        const uint32_t* __restrict__ wtab,    // [dc][4 dwords]
        float* __restrict__ S) {
    // sT[row][dc ^ (row&7)]: uint4 = {ep01, ep23, ip01, ip23} f16 pairs.
    // XOR swizzle: writes (lane=dc, row const) and reads (lane=row, dc
    // uniform) both land stride-1-equivalent on the 32 banks (8-cyc floor).
    __shared__ uint4 sT[64][64];               // 64 KB

    const int tid = threadIdx.x;
    const int nt  = blockIdx.x & 255;          // idx%8 = nt%8 -> bh siblings same XCD
    const int bh  = blockIdx.x >> 8;           // 0..1

    // ---- stage pattern tile: 8 iters, coalesced float4 reads along d
#pragma unroll
    for (int it = 0; it < 8; ++it) {
        int g   = it * 512 + tid;              // granule 0..4095
        int row = g >> 6;                      // wave-uniform (it*8 + wv)
        int dc  = g & 63;                      // = lane -> coalesced
        float4 x4 = *(const float4*)&patterns[((size_t)nt * 64 + row) * D_ + dc * 4];
        float xs[4] = {x4.x, x4.y, x4.z, x4.w};
        union { uint4 u; _Float16 h[8]; } o;
#pragma unroll
        for (int j = 0; j < 4; ++j) {
            float t  = exp2f(-xs[j] * kL2E);                // e^{-x}
            float sg = __fdividef(1.0f, 1.0f + t);          // sigmoid
            float u  = fmaf(-15.0f * kC2, sg, 20.0f * kC2); // pt/(3 ln2)
            o.h[j]     = (_Float16)exp2f(u);                // ep0
            o.h[4 + j] = (_Float16)exp2f(-u);               // ip0
        }
        sT[row][dc ^ (row & 7)] = o.u;
    }
    __syncthreads();

    const int l  = tid & 63;
    const int wv = tid >> 6;
    const int bg = __builtin_amdgcn_readfirstlane(bh * 8 + wv);  // 0..15
    const int b0 = bg * 4;
    const int lx = l & 7;

    float acc[4] = {0.f, 0.f, 0.f, 0.f};

    QB qA, qB; WB wA, wB;
    uint4 pA, pB;
    load_q(qarr, wtab, 0, bg, qA, wA);
    pA = sT[l][0 ^ lx];

    for (int dc = 0; dc < NCH - 2; dc += 2) {
        load_q(qarr, wtab, dc + 1, bg, qB, wB);
        pB = sT[l][(dc + 1) ^ lx];
        chunk_math(qA, wA, pA, acc);
        load_q(qarr, wtab, dc + 2, bg, qA, wA);
        pA = sT[l][(dc + 2) ^ lx];
        chunk_math(qB, wB, pB, acc);
    }
    load_q(qarr, wtab, NCH - 1, bg, qB, wB);
    pB = sT[l][(NCH - 1) ^ lx];
    chunk_math(qA, wA, pA, acc);      // chunk 62
    chunk_math(qB, wB, pB, acc);      // chunk 63

#pragma unroll
    for (int i = 0; i < 4; ++i)
        S[(size_t)(b0 + i) * N_ + nt * 64 + l] = acc[i];
}

extern "C" void kernel_launch(void* const* d_in, const int* in_sizes, int n_in,
                              void* d_out, int out_size, void* d_ws, size_t ws_size,
                              hipStream_t stream) {
    const float* q        = (const float*)d_in[0];
    const float* patterns = (const float*)d_in[1];
    const float* weights  = (const float*)d_in[2];
    float* S = (float*)d_out;

    // ws: qarr 65536 B | wtab 1024 B  (total 66.5 KB)
    uint32_t* qarr = (uint32_t*)d_ws;
    uint32_t* wtab = (uint32_t*)((char*)d_ws + 65536);

    pre_query<<<B_, 256, 0, stream>>>(q, weights, (_Float16*)qarr, (_Float16*)wtab);
    cd_main  <<<512, 512, 0, stream>>>(patterns, qarr, wtab, S);
}